// Round 4
// baseline (592.981 us; speedup 1.0000x reference)
//
#include <hip/hip_runtime.h>
#include <cstdint>
#include <cstddef>

#define BB 64
#define NN 1024
#define OBSN 64
#define ACTN 16
#define DTC 0.1f
// Python: ITERS = int(1.0 // 0.1) == 9  (0.1 rounds up in binary -> 1.0/0.1 = 9.9999... -> floor 9)
#define ITERS 9
#define QMAX 32704.0f

// ---------- helpers: signed 16-bit halves of a packed u32 -> float ----------
__device__ inline float s16lo(unsigned u) { return (float)((int)(u << 16) >> 16); }
__device__ inline float s16hi(unsigned u) { return (float)((int)u >> 16); }

// ================= path 1/2: multi-kernel =================

// W fp32 -> int16, per-row scale. One wave per row; block 256 = 4 rows.
__global__ __launch_bounds__(256) void k_quant(const float* __restrict__ W,
                                               short* __restrict__ Wq,
                                               float* __restrict__ scales) {
    int w = threadIdx.x >> 6, l = threadIdx.x & 63;
    int rid = blockIdx.x * 4 + w;                 // 0 .. B*N-1
    const float* rp = W + (size_t)rid * NN;
    float4 f[4];
    float mx = 0.f;
#pragma unroll
    for (int c = 0; c < 4; ++c) {
        f[c] = *(const float4*)(rp + c * 256 + 4 * l);
        mx = fmaxf(mx, fmaxf(fmaxf(fabsf(f[c].x), fabsf(f[c].y)),
                             fmaxf(fabsf(f[c].z), fabsf(f[c].w))));
    }
#pragma unroll
    for (int m = 32; m; m >>= 1) mx = fmaxf(mx, __shfl_xor(mx, m, 64));
    mx = fmaxf(mx, 1e-30f);
    float minv = QMAX / mx;
    short* op = Wq + (size_t)rid * NN;
#pragma unroll
    for (int c = 0; c < 4; ++c) {
        short4 q;
        q.x = (short)__float2int_rn(f[c].x * minv);
        q.y = (short)__float2int_rn(f[c].y * minv);
        q.z = (short)__float2int_rn(f[c].z * minv);
        q.w = (short)__float2int_rn(f[c].w * minv);
        *(short4*)(op + c * 256 + 4 * l) = q;
    }
    if (l == 0) scales[rid] = mx / QMAX;
}

// I = E @ obs ; v := v0
__global__ void k_encode(const float* __restrict__ E, const float* __restrict__ obs,
                         const float* __restrict__ v0, float* __restrict__ I,
                         float* __restrict__ vbuf) {
    int t = blockIdx.x * 256 + threadIdx.x;        // block spans one b (256 | 1024)
    int b = t >> 10;
    __shared__ float obss[OBSN];
    if (threadIdx.x < OBSN) obss[threadIdx.x] = obs[b * OBSN + threadIdx.x];
    __syncthreads();
    const float4* e4 = (const float4*)(E + (size_t)t * OBSN);
    float acc = 0.f;
#pragma unroll
    for (int c = 0; c < OBSN / 4; ++c) {
        float4 e = e4[c];
        acc += e.x * obss[4 * c] + e.y * obss[4 * c + 1] + e.z * obss[4 * c + 2] + e.w * obss[4 * c + 3];
    }
    I[t] = acc;
    vbuf[t] = v0[t];
}

// one scan step. grid: B*(N/64) blocks of 256; block = (b, 64-row chunk); wave = 16 rows.
template <bool QUANT>
__global__ __launch_bounds__(256) void k_iter(const void* __restrict__ Wv,
                                              const float* __restrict__ scales,
                                              const float* __restrict__ vin,
                                              float* __restrict__ vout,
                                              const float* __restrict__ I,
                                              const float* __restrict__ tau,
                                              const float* __restrict__ gain,
                                              const float* __restrict__ bias,
                                              const float* __restrict__ mask) {
    int b  = blockIdx.x >> 4;
    int rb = blockIdx.x & 15;
    int tid = threadIdx.x;
    __shared__ float ylds[NN];

    {   // y = tanh(gain*(v+bias)) * mask, 4 elements / thread
        int k = tid * 4;
        size_t g = (size_t)b * NN + k;
        float4 v4 = *(const float4*)(vin + g);
        float4 g4 = *(const float4*)(gain + g);
        float4 b4 = *(const float4*)(bias + g);
        float4 m4 = *(const float4*)(mask + g);
        float4 y;
        y.x = tanhf(g4.x * (v4.x + b4.x)) * m4.x;
        y.y = tanhf(g4.y * (v4.y + b4.y)) * m4.y;
        y.z = tanhf(g4.z * (v4.z + b4.z)) * m4.z;
        y.w = tanhf(g4.w * (v4.w + b4.w)) * m4.w;
        *(float4*)(ylds + k) = y;
    }
    __syncthreads();

    int w = tid >> 6, l = tid & 63;
    int row0 = rb * 64 + w * 16;
    float res = 0.f;

    if (QUANT) {
        float y0[8], y1[8];
#pragma unroll
        for (int j = 0; j < 8; ++j) {
            y0[j] = ylds[8 * l + j];
            y1[j] = ylds[512 + 8 * l + j];
        }
        const short* Wb = (const short*)Wv + ((size_t)b * NN + row0) * NN;
#pragma unroll 4
        for (int r = 0; r < 16; ++r) {
            const short* rp = Wb + (size_t)r * NN;
            uint4 a = *(const uint4*)(rp + 8 * l);          // 8 int16, k = 8l..
            uint4 c = *(const uint4*)(rp + 512 + 8 * l);    // 8 int16, k = 512+8l..
            float acc;
            acc = s16lo(a.x) * y0[0];
            acc = fmaf(s16hi(a.x), y0[1], acc);
            acc = fmaf(s16lo(a.y), y0[2], acc);
            acc = fmaf(s16hi(a.y), y0[3], acc);
            acc = fmaf(s16lo(a.z), y0[4], acc);
            acc = fmaf(s16hi(a.z), y0[5], acc);
            acc = fmaf(s16lo(a.w), y0[6], acc);
            acc = fmaf(s16hi(a.w), y0[7], acc);
            acc = fmaf(s16lo(c.x), y1[0], acc);
            acc = fmaf(s16hi(c.x), y1[1], acc);
            acc = fmaf(s16lo(c.y), y1[2], acc);
            acc = fmaf(s16hi(c.y), y1[3], acc);
            acc = fmaf(s16lo(c.z), y1[4], acc);
            acc = fmaf(s16hi(c.z), y1[5], acc);
            acc = fmaf(s16lo(c.w), y1[6], acc);
            acc = fmaf(s16hi(c.w), y1[7], acc);
#pragma unroll
            for (int m = 32; m; m >>= 1) acc += __shfl_xor(acc, m, 64);
            if (l == r) res = acc;
        }
    } else {
        float yv[4][4];
#pragma unroll
        for (int c = 0; c < 4; ++c)
#pragma unroll
            for (int j = 0; j < 4; ++j) yv[c][j] = ylds[c * 256 + 4 * l + j];
        const float* Wb = (const float*)Wv + ((size_t)b * NN + row0) * NN;
#pragma unroll 2
        for (int r = 0; r < 16; ++r) {
            const float* rp = Wb + (size_t)r * NN;
            float acc = 0.f;
#pragma unroll
            for (int c = 0; c < 4; ++c) {
                float4 f = *(const float4*)(rp + c * 256 + 4 * l);
                acc = fmaf(f.x, yv[c][0], acc);
                acc = fmaf(f.y, yv[c][1], acc);
                acc = fmaf(f.z, yv[c][2], acc);
                acc = fmaf(f.w, yv[c][3], acc);
            }
#pragma unroll
            for (int m = 32; m; m >>= 1) acc += __shfl_xor(acc, m, 64);
            if (l == r) res = acc;
        }
    }

    if (l < 16) {
        int row = row0 + l;
        size_t g = (size_t)b * NN + row;
        float wy = QUANT ? res * scales[g] : res;
        float vold = vin[g];
        float c = DTC / tau[g];
        float vnew = ((1.f - c) * vold + c * (wy + I[g])) * mask[g];
        vout[g] = vnew;
    }
}

// action = D @ v
__global__ void k_decode(const float* __restrict__ D, const float* __restrict__ v,
                         float* __restrict__ out) {
    int gw = (blockIdx.x * 256 + threadIdx.x) >> 6;   // 0..1023 output wave id
    int l = threadIdx.x & 63;
    int b = gw >> 4, a = gw & 15;
    const float* Dp = D + ((size_t)b * ACTN + a) * NN;
    const float* vp = v + (size_t)b * NN;
    float acc = 0.f;
#pragma unroll
    for (int c = 0; c < 4; ++c) {
        float4 d4 = *(const float4*)(Dp + c * 256 + 4 * l);
        float4 v4 = *(const float4*)(vp + c * 256 + 4 * l);
        acc = fmaf(d4.x, v4.x, acc);
        acc = fmaf(d4.y, v4.y, acc);
        acc = fmaf(d4.z, v4.z, acc);
        acc = fmaf(d4.w, v4.w, acc);
    }
#pragma unroll
    for (int m = 32; m; m >>= 1) acc += __shfl_xor(acc, m, 64);
    if (l == 0) out[b * ACTN + a] = acc;
}

// ================= path 3: fused, zero workspace =================
__global__ __launch_bounds__(1024) void k_fused(
    const float* __restrict__ obs, const float* __restrict__ v0,
    const float* __restrict__ tau, const float* __restrict__ gain,
    const float* __restrict__ bias, const float* __restrict__ W,
    const float* __restrict__ mask, const float* __restrict__ E,
    const float* __restrict__ D, float* __restrict__ out)
{
    const int b = blockIdx.x;
    const int t = threadIdx.x;
    const int w = t >> 6;
    const int l = t & 63;

    __shared__ float ylds[NN];
    __shared__ float wylds[NN];
    __shared__ float obss[OBSN];

    const size_t g = (size_t)b * NN + t;
    float v  = v0[g];
    const float gn = gain[g];
    const float bs = bias[g];
    const float mk = mask[g];
    const float cc = DTC / tau[g];

    if (t < OBSN) obss[t] = obs[b * OBSN + t];
    __syncthreads();

    {   // encode
        const int gq = l >> 4, sl = l & 15;
        const int n0 = w * 64;
        for (int jj = 0; jj < 16; ++jj) {
            const int r4 = n0 + jj * 4 + gq;
            const float4 e = *(const float4*)(E + ((size_t)b * NN + r4) * OBSN + 4 * sl);
            float p = e.x * obss[4 * sl] + e.y * obss[4 * sl + 1]
                    + e.z * obss[4 * sl + 2] + e.w * obss[4 * sl + 3];
#pragma unroll
            for (int m = 1; m < 16; m <<= 1) p += __shfl_xor(p, m, 64);
            if (sl == 0) wylds[r4] = p;
        }
    }
    __syncthreads();
    const float I = wylds[t];

    for (int it = 0; it < ITERS; ++it) {
        const float y = tanhf(gn * (v + bs)) * mk;
        ylds[t] = y;
        __syncthreads();

        float yv[4][4];
#pragma unroll
        for (int c = 0; c < 4; ++c)
#pragma unroll
            for (int j = 0; j < 4; ++j) yv[c][j] = ylds[c * 256 + 4 * l + j];

        const float* Wb = W + ((size_t)b * NN + (size_t)w * 64) * NN;
#pragma unroll 2
        for (int r = 0; r < 64; ++r) {
            const float* rp = Wb + (size_t)r * NN;
            float acc = 0.f;
#pragma unroll
            for (int c = 0; c < 4; ++c) {
                const float4 f = *(const float4*)(rp + c * 256 + 4 * l);
                acc = fmaf(f.x, yv[c][0], acc);
                acc = fmaf(f.y, yv[c][1], acc);
                acc = fmaf(f.z, yv[c][2], acc);
                acc = fmaf(f.w, yv[c][3], acc);
            }
#pragma unroll
            for (int m = 32; m; m >>= 1) acc += __shfl_xor(acc, m, 64);
            if (l == 0) wylds[w * 64 + r] = acc;
        }
        __syncthreads();

        const float wy = wylds[t];
        v = ((1.f - cc) * v + cc * (wy + I)) * mk;
    }

    ylds[t] = v;
    __syncthreads();
    {
        const float* Dp = D + ((size_t)b * ACTN + w) * NN;
        float acc = 0.f;
#pragma unroll
        for (int c = 0; c < 4; ++c) {
            const float4 d4 = *(const float4*)(Dp + c * 256 + 4 * l);
            acc = fmaf(d4.x, ylds[c * 256 + 4 * l + 0], acc);
            acc = fmaf(d4.y, ylds[c * 256 + 4 * l + 1], acc);
            acc = fmaf(d4.z, ylds[c * 256 + 4 * l + 2], acc);
            acc = fmaf(d4.w, ylds[c * 256 + 4 * l + 3], acc);
        }
#pragma unroll
        for (int m = 32; m; m >>= 1) acc += __shfl_xor(acc, m, 64);
        if (l == 0) out[(size_t)b * ACTN + w] = acc;
    }
}

extern "C" void kernel_launch(void* const* d_in, const int* in_sizes, int n_in,
                              void* d_out, int out_size, void* d_ws, size_t ws_size,
                              hipStream_t stream) {
    const float* obs  = (const float*)d_in[0];
    const float* v0   = (const float*)d_in[1];
    const float* tau  = (const float*)d_in[2];
    const float* gain = (const float*)d_in[3];
    const float* bias = (const float*)d_in[4];
    const float* W    = (const float*)d_in[5];
    const float* mask = (const float*)d_in[6];
    const float* E    = (const float*)d_in[7];
    const float* D    = (const float*)d_in[8];
    float* out = (float*)d_out;
    (void)in_sizes; (void)n_in; (void)out_size;

    const size_t wq_bytes = (size_t)BB * NN * NN * 2;            // 134 MB int16 W
    const size_t sc_bytes = (size_t)BB * NN * 4;                 // per-row scales
    const size_t small_bytes = 3 * (size_t)BB * NN * 4;          // I + 2 v buffers
    char* ws = (char*)d_ws;

    const bool quant = (ws_size >= wq_bytes + sc_bytes + small_bytes);
    const bool multi = (ws_size >= small_bytes);

    if (multi) {
        short* Wq = (short*)ws;
        size_t off = quant ? (wq_bytes + sc_bytes) : 0;
        float* scales = (float*)(ws + wq_bytes);
        float* Ibuf = (float*)(ws + off);
        float* vb0 = Ibuf + BB * NN;
        float* vb1 = vb0 + BB * NN;

        if (quant) k_quant<<<BB * NN / 4, 256, 0, stream>>>(W, Wq, scales);
        k_encode<<<BB * NN / 256, 256, 0, stream>>>(E, obs, v0, Ibuf, vb0);

        float* vin = vb0;
        float* vout = vb1;
        for (int i = 0; i < ITERS; ++i) {
            if (quant)
                k_iter<true><<<BB * (NN / 64), 256, 0, stream>>>(Wq, scales, vin, vout, Ibuf, tau, gain, bias, mask);
            else
                k_iter<false><<<BB * (NN / 64), 256, 0, stream>>>(W, nullptr, vin, vout, Ibuf, tau, gain, bias, mask);
            float* tmp = vin; vin = vout; vout = tmp;
        }
        k_decode<<<256, 256, 0, stream>>>(D, vin, out);
    } else {
        k_fused<<<BB, 1024, 0, stream>>>(obs, v0, tau, gain, bias, W, mask, E, D, out);
    }
}